// Round 1
// baseline (6590.121 us; speedup 1.0000x reference)
//
#include <hip/hip_runtime.h>
#include <math.h>

namespace {

constexpr int Bb = 4, Ss = 512, Hh = 512, NHh = 8, HDh = 64;
constexpr int Ee = 8, Ll = 6, Vv = 50000, Ff = 2048;
constexpr int Tt = Bb * Ss;   // 2048 tokens
constexpr float LN_EPS = 1e-5f;

__device__ __forceinline__ float blockReduceSum128(float v, float* sbuf) {
#pragma unroll
  for (int mm = 1; mm < 64; mm <<= 1) v += __shfl_xor(v, mm, 64);
  int wid = threadIdx.x >> 6;
  if ((threadIdx.x & 63) == 0) sbuf[wid] = v;
  __syncthreads();
  float r = sbuf[0] + sbuf[1];
  __syncthreads();
  return r;
}

// ---------------- embedding ----------------
__global__ __launch_bounds__(128) void k_embed(const int* __restrict__ ids,
                                               const float* __restrict__ tok,
                                               const float* __restrict__ pos,
                                               float* __restrict__ x) {
  int t = blockIdx.x;
  int s = t & (Ss - 1);
  long id = ids[t];
  const float4* tp = reinterpret_cast<const float4*>(tok + id * Hh);
  const float4* pp = reinterpret_cast<const float4*>(pos + (long)s * Hh);
  float4* xp = reinterpret_cast<float4*>(x + (long)t * Hh);
  int i = threadIdx.x;
  float4 a = tp[i], b = pp[i];
  xp[i] = make_float4(a.x + b.x, a.y + b.y, a.z + b.z, a.w + b.w);
}

// ---------------- GEMM: C(M,N) = A(M,Kd) @ B(N,Kd)^T + bias ----------------
template <int BN>
__global__ __launch_bounds__(256) void k_gemm_nt(const float* __restrict__ A,
                                                 const float* __restrict__ Bm,
                                                 const float* __restrict__ bias,
                                                 float* __restrict__ C, int N, int Kd) {
  constexpr int TN = BN / 16;
  __shared__ float As[16][68];
  __shared__ float Bs[16][BN + 4];
  int tid = threadIdx.x;
  int bm = blockIdx.y * 64, bn = blockIdx.x * BN;
  int tm = (tid & 15) * 4, tn = (tid >> 4) * TN;
  float acc[4][TN];
#pragma unroll
  for (int i = 0; i < 4; ++i)
#pragma unroll
    for (int j = 0; j < TN; ++j) acc[i][j] = 0.f;
  int alr = tid >> 2, alc = tid & 3;
  for (int k0 = 0; k0 < Kd; k0 += 16) {
    float4 av = *reinterpret_cast<const float4*>(A + (long)(bm + alr) * Kd + k0 + alc * 4);
    As[alc * 4 + 0][alr] = av.x; As[alc * 4 + 1][alr] = av.y;
    As[alc * 4 + 2][alr] = av.z; As[alc * 4 + 3][alr] = av.w;
#pragma unroll
    for (int i = 0; i < BN / 64; ++i) {
      int j = i * 256 + tid;
      int br = j >> 2, bc = j & 3;
      float4 bv = *reinterpret_cast<const float4*>(Bm + (long)(bn + br) * Kd + k0 + bc * 4);
      Bs[bc * 4 + 0][br] = bv.x; Bs[bc * 4 + 1][br] = bv.y;
      Bs[bc * 4 + 2][br] = bv.z; Bs[bc * 4 + 3][br] = bv.w;
    }
    __syncthreads();
#pragma unroll
    for (int k = 0; k < 16; ++k) {
      float a[4], b[TN];
      float4 a4 = *reinterpret_cast<const float4*>(&As[k][tm]);
      a[0] = a4.x; a[1] = a4.y; a[2] = a4.z; a[3] = a4.w;
#pragma unroll
      for (int u = 0; u < TN / 4; ++u) {
        float4 b4 = *reinterpret_cast<const float4*>(&Bs[k][tn + u * 4]);
        b[u * 4 + 0] = b4.x; b[u * 4 + 1] = b4.y; b[u * 4 + 2] = b4.z; b[u * 4 + 3] = b4.w;
      }
#pragma unroll
      for (int i = 0; i < 4; ++i)
#pragma unroll
        for (int j = 0; j < TN; ++j) acc[i][j] = fmaf(a[i], b[j], acc[i][j]);
    }
    __syncthreads();
  }
#pragma unroll
  for (int i = 0; i < 4; ++i) {
    long crow = (long)(bm + tm + i) * N;
#pragma unroll
    for (int j = 0; j < TN; ++j) {
      int n = bn + tn + j;
      if (n < N) C[crow + n] = acc[i][j] + bias[n];
    }
  }
}

// ---------------- GEMM: C(M,N) = A(M,Kd) @ B(Kd,N) + bias ----------------
template <int BN>
__global__ __launch_bounds__(256) void k_gemm_nn(const float* __restrict__ A,
                                                 const float* __restrict__ Bm,
                                                 const float* __restrict__ bias,
                                                 float* __restrict__ C, int N, int Kd) {
  constexpr int TN = BN / 16;
  constexpr int C4 = BN / 4;
  __shared__ float As[16][68];
  __shared__ float Bs[16][BN + 4];
  int tid = threadIdx.x;
  int bm = blockIdx.y * 64, bn = blockIdx.x * BN;
  int tm = (tid & 15) * 4, tn = (tid >> 4) * TN;
  float acc[4][TN];
#pragma unroll
  for (int i = 0; i < 4; ++i)
#pragma unroll
    for (int j = 0; j < TN; ++j) acc[i][j] = 0.f;
  int alr = tid >> 2, alc = tid & 3;
  for (int k0 = 0; k0 < Kd; k0 += 16) {
    float4 av = *reinterpret_cast<const float4*>(A + (long)(bm + alr) * Kd + k0 + alc * 4);
    As[alc * 4 + 0][alr] = av.x; As[alc * 4 + 1][alr] = av.y;
    As[alc * 4 + 2][alr] = av.z; As[alc * 4 + 3][alr] = av.w;
#pragma unroll
    for (int i = 0; i < BN / 64; ++i) {
      int j = i * 256 + tid;
      int brr = j / C4, bcc = j % C4;
      int n = bn + bcc * 4;
      float4 bv = make_float4(0.f, 0.f, 0.f, 0.f);
      if (n < N) bv = *reinterpret_cast<const float4*>(Bm + (long)(k0 + brr) * N + n);
      *reinterpret_cast<float4*>(&Bs[brr][bcc * 4]) = bv;
    }
    __syncthreads();
#pragma unroll
    for (int k = 0; k < 16; ++k) {
      float a[4], b[TN];
      float4 a4 = *reinterpret_cast<const float4*>(&As[k][tm]);
      a[0] = a4.x; a[1] = a4.y; a[2] = a4.z; a[3] = a4.w;
#pragma unroll
      for (int u = 0; u < TN / 4; ++u) {
        float4 b4 = *reinterpret_cast<const float4*>(&Bs[k][tn + u * 4]);
        b[u * 4 + 0] = b4.x; b[u * 4 + 1] = b4.y; b[u * 4 + 2] = b4.z; b[u * 4 + 3] = b4.w;
      }
#pragma unroll
      for (int i = 0; i < 4; ++i)
#pragma unroll
        for (int j = 0; j < TN; ++j) acc[i][j] = fmaf(a[i], b[j], acc[i][j]);
    }
    __syncthreads();
  }
#pragma unroll
  for (int i = 0; i < 4; ++i) {
    long crow = (long)(bm + tm + i) * N;
#pragma unroll
    for (int j = 0; j < TN; ++j) {
      int n = bn + tn + j;
      if (n < N) C[crow + n] = acc[i][j] + bias[n];
    }
  }
}

// ------------- expert GEMM (NN, gathered rows, optional exact GELU) -------------
template <int BN, bool GELU>
__global__ __launch_bounds__(256) void k_expert_gemm(const float* __restrict__ Ab,
                                                     const float* __restrict__ W,
                                                     const float* __restrict__ bias,
                                                     float* __restrict__ C,
                                                     const int* __restrict__ off,
                                                     const int* __restrict__ cnt,
                                                     int N, int Kd) {
  constexpr int TN = BN / 16;
  constexpr int C4 = BN / 4;
  int e = blockIdx.z;
  int count = cnt[e];
  int rb = blockIdx.y * 64;
  if (rb >= count) return;
  int base = off[e];
  const float* Wp = W + (long)e * Kd * N;
  const float* bp = bias + (long)e * N;
  __shared__ float As[16][68];
  __shared__ float Bs[16][BN + 4];
  int tid = threadIdx.x;
  int bn = blockIdx.x * BN;
  int tm = (tid & 15) * 4, tn = (tid >> 4) * TN;
  float acc[4][TN];
#pragma unroll
  for (int i = 0; i < 4; ++i)
#pragma unroll
    for (int j = 0; j < TN; ++j) acc[i][j] = 0.f;
  int alr = tid >> 2, alc = tid & 3;
  int arl = rb + alr;
  long arow = base + (arl < count ? arl : 0);
  for (int k0 = 0; k0 < Kd; k0 += 16) {
    float4 av = *reinterpret_cast<const float4*>(Ab + arow * Kd + k0 + alc * 4);
    As[alc * 4 + 0][alr] = av.x; As[alc * 4 + 1][alr] = av.y;
    As[alc * 4 + 2][alr] = av.z; As[alc * 4 + 3][alr] = av.w;
#pragma unroll
    for (int i = 0; i < BN / 64; ++i) {
      int j = i * 256 + tid;
      int brr = j / C4, bcc = j % C4;
      float4 bv = *reinterpret_cast<const float4*>(Wp + (long)(k0 + brr) * N + bn + bcc * 4);
      *reinterpret_cast<float4*>(&Bs[brr][bcc * 4]) = bv;
    }
    __syncthreads();
#pragma unroll
    for (int k = 0; k < 16; ++k) {
      float a[4], b[TN];
      float4 a4 = *reinterpret_cast<const float4*>(&As[k][tm]);
      a[0] = a4.x; a[1] = a4.y; a[2] = a4.z; a[3] = a4.w;
#pragma unroll
      for (int u = 0; u < TN / 4; ++u) {
        float4 b4 = *reinterpret_cast<const float4*>(&Bs[k][tn + u * 4]);
        b[u * 4 + 0] = b4.x; b[u * 4 + 1] = b4.y; b[u * 4 + 2] = b4.z; b[u * 4 + 3] = b4.w;
      }
#pragma unroll
      for (int i = 0; i < 4; ++i)
#pragma unroll
        for (int j = 0; j < TN; ++j) acc[i][j] = fmaf(a[i], b[j], acc[i][j]);
    }
    __syncthreads();
  }
#pragma unroll
  for (int i = 0; i < 4; ++i) {
    int rl = rb + tm + i;
    if (rl < count) {
      long crow = (long)(base + rl) * N;
#pragma unroll
      for (int j = 0; j < TN; ++j) {
        float v = acc[i][j] + bp[bn + tn + j];
        if (GELU) v = 0.5f * v * (1.f + erff(v * 0.70710678118654752f));
        C[crow + bn + tn + j] = v;
      }
    }
  }
}

// ---------------- streaming attention (online softmax) ----------------
__global__ __launch_bounds__(256) void k_attn(const float* __restrict__ qkv,
                                              float* __restrict__ ao) {
  __shared__ float qs[16][68];
  __shared__ float ks[64][68];
  __shared__ float vs[64][68];
  __shared__ float ps[16][64];
  int bh = blockIdx.y;
  int b = bh >> 3, h = bh & 7;
  int q0 = blockIdx.x * 16;
  int tid = threadIdx.x;
  int r = tid >> 4, c = tid & 15;
  {
    const float4* src = reinterpret_cast<const float4*>(
        qkv + (long)(b * Ss + q0 + r) * (3 * Hh) + h * HDh);
    *reinterpret_cast<float4*>(&qs[r][c * 4]) = src[c];
  }
  float m_i = -1e30f, l_i = 0.f;
  float o0 = 0.f, o1 = 0.f, o2 = 0.f, o3 = 0.f;
  for (int kt = 0; kt < Ss; kt += 64) {
    __syncthreads();
#pragma unroll
    for (int i = 0; i < 4; ++i) {
      int j = i * 256 + tid;
      int kr = j >> 4, kc = j & 15;
      const float* kbase = qkv + (long)(b * Ss + kt + kr) * (3 * Hh) + h * HDh;
      *reinterpret_cast<float4*>(&ks[kr][kc * 4]) =
          reinterpret_cast<const float4*>(kbase + Hh)[kc];
      *reinterpret_cast<float4*>(&vs[kr][kc * 4]) =
          reinterpret_cast<const float4*>(kbase + 2 * Hh)[kc];
    }
    __syncthreads();
    float sc[4] = {0.f, 0.f, 0.f, 0.f};
#pragma unroll
    for (int d = 0; d < 64; d += 4) {
      float4 qv = *reinterpret_cast<const float4*>(&qs[r][d]);
#pragma unroll
      for (int j = 0; j < 4; ++j) {
        float4 kv = *reinterpret_cast<const float4*>(&ks[c * 4 + j][d]);
        sc[j] += qv.x * kv.x + qv.y * kv.y + qv.z * kv.z + qv.w * kv.w;
      }
    }
#pragma unroll
    for (int j = 0; j < 4; ++j) sc[j] *= 0.125f;
    float mx = fmaxf(fmaxf(sc[0], sc[1]), fmaxf(sc[2], sc[3]));
#pragma unroll
    for (int mm = 1; mm < 16; mm <<= 1) mx = fmaxf(mx, __shfl_xor(mx, mm, 64));
    float m_new = fmaxf(m_i, mx);
    float alpha = expf(m_i - m_new);
    float p0 = expf(sc[0] - m_new), p1 = expf(sc[1] - m_new);
    float p2 = expf(sc[2] - m_new), p3 = expf(sc[3] - m_new);
    float ls = p0 + p1 + p2 + p3;
#pragma unroll
    for (int mm = 1; mm < 16; mm <<= 1) ls += __shfl_xor(ls, mm, 64);
    l_i = l_i * alpha + ls;
    m_i = m_new;
    o0 *= alpha; o1 *= alpha; o2 *= alpha; o3 *= alpha;
    *reinterpret_cast<float4*>(&ps[r][c * 4]) = make_float4(p0, p1, p2, p3);
    __syncthreads();
#pragma unroll 16
    for (int kk = 0; kk < 64; ++kk) {
      float pv = ps[r][kk];
      float4 vv = *reinterpret_cast<const float4*>(&vs[kk][c * 4]);
      o0 = fmaf(pv, vv.x, o0); o1 = fmaf(pv, vv.y, o1);
      o2 = fmaf(pv, vv.z, o2); o3 = fmaf(pv, vv.w, o3);
    }
  }
  float invl = 1.f / l_i;
  *reinterpret_cast<float4*>(ao + (long)(b * Ss + q0 + r) * Hh + h * HDh + c * 4) =
      make_float4(o0 * invl, o1 * invl, o2 * invl, o3 * invl);
}

// ---------------- x = LN(x + a) ----------------
__global__ __launch_bounds__(128) void k_add_ln(float* __restrict__ x,
                                                const float* __restrict__ a,
                                                const float* __restrict__ g,
                                                const float* __restrict__ b) {
  __shared__ float sbuf[2];
  int t = blockIdx.x, tid = threadIdx.x;
  float4 xv = reinterpret_cast<const float4*>(x + (long)t * Hh)[tid];
  float4 av = reinterpret_cast<const float4*>(a + (long)t * Hh)[tid];
  float sx = xv.x + av.x, sy = xv.y + av.y, sz = xv.z + av.z, sw = xv.w + av.w;
  float sum = blockReduceSum128(sx + sy + sz + sw, sbuf);
  float mean = sum * (1.f / Hh);
  float dx = sx - mean, dy = sy - mean, dz = sz - mean, dw = sw - mean;
  float sq = blockReduceSum128(dx * dx + dy * dy + dz * dz + dw * dw, sbuf);
  float inv = rsqrtf(sq * (1.f / Hh) + LN_EPS);
  float4 g4 = reinterpret_cast<const float4*>(g)[tid];
  float4 b4 = reinterpret_cast<const float4*>(b)[tid];
  reinterpret_cast<float4*>(x + (long)t * Hh)[tid] =
      make_float4(dx * inv * g4.x + b4.x, dy * inv * g4.y + b4.y,
                  dz * inv * g4.z + b4.z, dw * inv * g4.w + b4.w);
}

// ---------------- router: logits, top-2, softmax, counts ----------------
__global__ __launch_bounds__(64) void k_router(const float* __restrict__ x,
                                               const float* __restrict__ rw,
                                               const float* __restrict__ rb,
                                               float* __restrict__ topw,
                                               int* __restrict__ topi,
                                               int* __restrict__ counts) {
  int t = blockIdx.x, lane = threadIdx.x;
  float acc[Ee];
#pragma unroll
  for (int e = 0; e < Ee; ++e) acc[e] = 0.f;
  const float* xr = x + (long)t * Hh;
  for (int hh = lane; hh < Hh; hh += 64) {
    float xv = xr[hh];
#pragma unroll
    for (int e = 0; e < Ee; ++e) acc[e] += xv * rw[hh * Ee + e];
  }
#pragma unroll
  for (int e = 0; e < Ee; ++e) {
#pragma unroll
    for (int mm = 1; mm < 64; mm <<= 1) acc[e] += __shfl_xor(acc[e], mm, 64);
  }
  if (lane == 0) {
    float l[Ee];
#pragma unroll
    for (int e = 0; e < Ee; ++e) l[e] = acc[e] + rb[e];
    int i0 = 0; float v0 = l[0];
#pragma unroll
    for (int e = 1; e < Ee; ++e) if (l[e] > v0) { v0 = l[e]; i0 = e; }
    int i1 = -1; float v1 = -3.4e38f;
#pragma unroll
    for (int e = 0; e < Ee; ++e) if (e != i0 && l[e] > v1) { v1 = l[e]; i1 = e; }
    float ew = expf(v1 - v0);
    float den = 1.f + ew;
    topw[2 * t] = 1.f / den;
    topw[2 * t + 1] = ew / den;
    topi[2 * t] = i0; topi[2 * t + 1] = i1;
    atomicAdd(&counts[i0], 1);
    atomicAdd(&counts[i1], 1);
  }
}

__global__ void k_zero_counts(int* __restrict__ counts) {
  if (threadIdx.x < Ee) counts[threadIdx.x] = 0;
}

__global__ void k_scan(const int* __restrict__ counts, int* __restrict__ off,
                       int* __restrict__ cursor) {
  if (threadIdx.x == 0) {
    int o = 0;
    for (int e = 0; e < Ee; ++e) { off[e] = o; o += counts[e]; cursor[e] = 0; }
    off[Ee] = o;
  }
}

// ---------------- per-pair expert-LN gather ----------------
__global__ __launch_bounds__(128) void k_gather_ln(const float* __restrict__ x,
                                                   const float* __restrict__ eg,
                                                   const float* __restrict__ eb,
                                                   const int* __restrict__ topi,
                                                   const int* __restrict__ off,
                                                   int* __restrict__ cursor,
                                                   int* __restrict__ ppos,
                                                   float* __restrict__ yg) {
  __shared__ float sbuf[2];
  __shared__ int ps_[2];
  int t = blockIdx.x, tid = threadIdx.x;
  float4 v = reinterpret_cast<const float4*>(x + (long)t * Hh)[tid];
  float sum = blockReduceSum128(v.x + v.y + v.z + v.w, sbuf);
  float mean = sum * (1.f / Hh);
  float dx = v.x - mean, dy = v.y - mean, dz = v.z - mean, dw = v.w - mean;
  float sq = blockReduceSum128(dx * dx + dy * dy + dz * dz + dw * dw, sbuf);
  float inv = rsqrtf(sq * (1.f / Hh) + LN_EPS);
  if (tid == 0) {
#pragma unroll
    for (int k = 0; k < 2; ++k) {
      int e = topi[2 * t + k];
      int p = off[e] + atomicAdd(&cursor[e], 1);
      ppos[2 * t + k] = p;
      ps_[k] = p;
    }
  }
  __syncthreads();
#pragma unroll
  for (int k = 0; k < 2; ++k) {
    int e = topi[2 * t + k];
    long p = ps_[k];
    float4 g4 = reinterpret_cast<const float4*>(eg + (long)e * Hh)[tid];
    float4 b4 = reinterpret_cast<const float4*>(eb + (long)e * Hh)[tid];
    reinterpret_cast<float4*>(yg + p * Hh)[tid] =
        make_float4(dx * inv * g4.x + b4.x, dy * inv * g4.y + b4.y,
                    dz * inv * g4.z + b4.z, dw * inv * g4.w + b4.w);
  }
}

// ---------------- combine experts + residual + LN ----------------
__global__ __launch_bounds__(128) void k_combine_ln(float* __restrict__ x,
                                                    const float* __restrict__ eo,
                                                    const float* __restrict__ topw,
                                                    const int* __restrict__ ppos,
                                                    const float* __restrict__ g,
                                                    const float* __restrict__ b) {
  __shared__ float sbuf[2];
  int t = blockIdx.x, tid = threadIdx.x;
  long p0 = ppos[2 * t], p1 = ppos[2 * t + 1];
  float w0 = topw[2 * t], w1 = topw[2 * t + 1];
  float4 xv = reinterpret_cast<const float4*>(x + (long)t * Hh)[tid];
  float4 e0 = reinterpret_cast<const float4*>(eo + p0 * Hh)[tid];
  float4 e1 = reinterpret_cast<const float4*>(eo + p1 * Hh)[tid];
  float sx = 2.f * xv.x + w0 * e0.x + w1 * e1.x;
  float sy = 2.f * xv.y + w0 * e0.y + w1 * e1.y;
  float sz = 2.f * xv.z + w0 * e0.z + w1 * e1.z;
  float sw = 2.f * xv.w + w0 * e0.w + w1 * e1.w;
  float sum = blockReduceSum128(sx + sy + sz + sw, sbuf);
  float mean = sum * (1.f / Hh);
  float dx = sx - mean, dy = sy - mean, dz = sz - mean, dw = sw - mean;
  float sq = blockReduceSum128(dx * dx + dy * dy + dz * dz + dw * dw, sbuf);
  float inv = rsqrtf(sq * (1.f / Hh) + LN_EPS);
  float4 g4 = reinterpret_cast<const float4*>(g)[tid];
  float4 b4 = reinterpret_cast<const float4*>(b)[tid];
  reinterpret_cast<float4*>(x + (long)t * Hh)[tid] =
      make_float4(dx * inv * g4.x + b4.x, dy * inv * g4.y + b4.y,
                  dz * inv * g4.z + b4.z, dw * inv * g4.w + b4.w);
}

}  // namespace

extern "C" void kernel_launch(void* const* d_in, const int* in_sizes, int n_in,
                              void* d_out, int out_size, void* d_ws, size_t ws_size,
                              hipStream_t stream) {
  const int*   ids   = (const int*)d_in[0];
  const float* tok   = (const float*)d_in[1];
  const float* pos   = (const float*)d_in[2];
  const float* w_qkv = (const float*)d_in[3];
  const float* b_qkv = (const float*)d_in[4];
  const float* w_o   = (const float*)d_in[5];
  const float* b_o   = (const float*)d_in[6];
  const float* ln_g  = (const float*)d_in[7];
  const float* ln_b  = (const float*)d_in[8];
  const float* rw    = (const float*)d_in[9];
  const float* rbias = (const float*)d_in[10];
  const float* eg    = (const float*)d_in[11];
  const float* eb    = (const float*)d_in[12];
  const float* w1    = (const float*)d_in[13];
  const float* b1    = (const float*)d_in[14];
  const float* w2    = (const float*)d_in[15];
  const float* b2    = (const float*)d_in[16];
  const float* w_out = (const float*)d_in[17];
  const float* b_out = (const float*)d_in[18];
  float* out = (float*)d_out;

  // workspace layout (floats)
  float* ws   = (float*)d_ws;
  float* x    = ws;                          // T*H      = 1M
  float* qkvb = x + (long)Tt * Hh;           // T*3H     = 3M
  float* aob  = qkvb + (long)Tt * 3 * Hh;    // T*H
  float* aprj = aob + (long)Tt * Hh;         // T*H
  float* yg   = aprj + (long)Tt * Hh;        // 2T*H     = 2M
  float* topw = yg + (long)2 * Tt * Hh;      // 2T
  int* topi   = (int*)(topw + 2 * Tt);       // 2T
  int* ppos   = topi + 2 * Tt;               // 2T
  int* counts = ppos + 2 * Tt;               // E
  int* off    = counts + Ee;                 // E+1
  int* cursor = off + Ee + 1;                // E
  size_t need = (size_t)((char*)(cursor + Ee) - (char*)d_ws);
  if (ws_size < need) return;  // ws too small: bail (visible as validation failure)

  // big MoE scratch lives in d_out (409 MB; fully rewritten by final GEMM)
  float* hbuf = out;                         // 2T*F = 8M floats
  float* eo   = out + (long)2 * Tt * Ff;     // 2T*H = 2M floats

  k_embed<<<Tt, 128, 0, stream>>>(ids, tok, pos, x);
  for (int l = 0; l < Ll; ++l) {
    k_gemm_nt<128><<<dim3(3 * Hh / 128, Tt / 64), 256, 0, stream>>>(
        x, w_qkv, b_qkv, qkvb, 3 * Hh, Hh);
    k_attn<<<dim3(Ss / 16, Bb * NHh), 256, 0, stream>>>(qkvb, aob);
    k_gemm_nt<64><<<dim3(Hh / 64, Tt / 64), 256, 0, stream>>>(
        aob, w_o, b_o, aprj, Hh, Hh);
    k_add_ln<<<Tt, 128, 0, stream>>>(x, aprj, ln_g, ln_b);
    k_zero_counts<<<1, 64, 0, stream>>>(counts);
    k_router<<<Tt, 64, 0, stream>>>(x, rw + (long)l * Hh * Ee, rbias + l * Ee,
                                    topw, topi, counts);
    k_scan<<<1, 1, 0, stream>>>(counts, off, cursor);
    k_gather_ln<<<Tt, 128, 0, stream>>>(x, eg + (long)l * Ee * Hh,
                                        eb + (long)l * Ee * Hh, topi, off, cursor,
                                        ppos, yg);
    k_expert_gemm<128, true><<<dim3(Ff / 128, Tt / 64, Ee), 256, 0, stream>>>(
        yg, w1 + (long)l * Ee * Hh * Ff, b1 + (long)l * Ee * Ff, hbuf, off, counts,
        Ff, Hh);
    k_expert_gemm<64, false><<<dim3(Hh / 64, Tt / 64, Ee), 256, 0, stream>>>(
        hbuf, w2 + (long)l * Ee * Ff * Hh, b2 + (long)l * Ee * Hh, eo, off, counts,
        Hh, Ff);
    k_combine_ln<<<Tt, 128, 0, stream>>>(x, eo, topw, ppos, ln_g, ln_b);
  }
  k_gemm_nn<128><<<dim3((Vv + 127) / 128, Tt / 64), 256, 0, stream>>>(
      x, w_out, b_out, out, Vv, Hh);
}